// Round 14
// baseline (250.121 us; speedup 1.0000x reference)
//
#include <hip/hip_runtime.h>

// LowRankRotatedSpaceIntervention — v14 = v8 structure at BM=64 (footprint).
// out[b,:] = base[b,:] + (mask_b . ((source[b,:]-base[b,:]) @ W)) @ W^T
// B=16384, D=4096, R=64, 8 partitions of 8, 4 selected per row.
//
// Only robust signal after 13 rounds: BW is monotone in rows-per-block
// (BM 4/8/16/32 -> 1.0/1.8/2.35/2.8 TB/s) while occupancy, pipeline depth,
// vmcnt ledger, contiguity, W placement, XCD remap are all neutral. v14
// doubles the footprint again: BM=64, 256 blocks x 512 threads, 8 waves =
// (4 row-quarters x 2 K-halves). Per-wave shape identical to v8 (16 rows x
// 2048-col half, 64-col chunks, ring-2 prefetch, compiler-scheduled waits,
// register W loads). LDS 137 KB -> 1 block/CU, still 8 waves/CU.

#define D_DIM 4096
#define R_DIM 64
#define BM    64
#define WAVESTG 16384            // per-wave staging: 2 buffers x 8KB
#define OFF_RM  131072           // [64][72] bf16 = 9216 B
#define SMEM_BYTES 140288        // 1 block/CU (137 KB)

typedef short bf16vec8 __attribute__((ext_vector_type(8)));
typedef float f32x4v  __attribute__((ext_vector_type(4)));

__device__ __forceinline__ unsigned int f2bf_u(float f) {
  unsigned int u = __builtin_bit_cast(unsigned int, f);
  return (u + 0x7fffu + ((u >> 16) & 1u)) >> 16;   // RNE
}
__device__ __forceinline__ unsigned int pack2bf(float a, float b) {
  return f2bf_u(a) | (f2bf_u(b) << 16);
}
__device__ __forceinline__ void async_ld16(const void* g, void* l) {
  __builtin_amdgcn_global_load_lds(
      (const __attribute__((address_space(1))) void*)g,
      (__attribute__((address_space(3))) void*)l, 16, 0, 0);
}

__global__ __launch_bounds__(256)
void lrri_prep(const float* __restrict__ W, unsigned short* __restrict__ Wt,
               unsigned short* __restrict__ Wb) {
  const int idx = blockIdx.x * blockDim.x + threadIdx.x;   // 0..65535
  const int k = idx >> 4;
  const int j = (idx & 15) * 4;
  float4 w = *(const float4*)(W + (size_t)k * R_DIM + j);
  ushort4 p;
  p.x = (unsigned short)f2bf_u(w.x);
  p.y = (unsigned short)f2bf_u(w.y);
  p.z = (unsigned short)f2bf_u(w.z);
  p.w = (unsigned short)f2bf_u(w.w);
  *(ushort4*)(Wb + (size_t)k * R_DIM + j) = p;     // [4096][64] bf16
  Wt[(size_t)(j + 0) * D_DIM + k] = p.x;           // [64][4096] bf16
  Wt[(size_t)(j + 1) * D_DIM + k] = p.y;
  Wt[(size_t)(j + 2) * D_DIM + k] = p.z;
  Wt[(size_t)(j + 3) * D_DIM + k] = p.w;
}

template<bool USE_WS>
__global__ __launch_bounds__(512, 1)
void lrri_fused(const float* __restrict__ base, const float* __restrict__ srcp,
                const float* __restrict__ W, const int* __restrict__ subs,
                const unsigned short* __restrict__ Wt_bf,   // [64][4096]
                const unsigned short* __restrict__ Wb_bf,   // [4096][64]
                float* __restrict__ out)
{
  __shared__ __align__(16) unsigned char smem[SMEM_BYTES];
  const int tid  = threadIdx.x;
  const int wave = tid >> 6;             // 0..7
  const int lane = tid & 63;
  const int l4   = lane & 15;
  const int g    = lane >> 4;
  const int rq   = wave >> 1;            // row-quarter: 16 rows
  const int kh   = wave & 1;             // K-half: 2048 cols
  // XCD-aware bijective remap (neutral but harmless): 256 = 8 x 32
  const int tile = (blockIdx.x & 7) * 32 + (blockIdx.x >> 3);
  const long rowbase = (long)tile * BM;
  const long rowg    = rowbase + rq * 16;
  unsigned char* wbuf = smem + wave * WAVESTG;
  const int off1 = (tile * 7) & 31;
  const int off2 = (tile * 5) & 31;

  // ---------------- Phase 1: r = (src-base) @ W over this wave's K half ---
  f32x4v acc[4];
  #pragma unroll
  for (int t = 0; t < 4; ++t) acc[t] = (f32x4v){0.f, 0.f, 0.f, 0.f};

  // stage one 64-float K-chunk of base+src for 16 rows into buffer p (8KB)
  auto stage = [&](int p, int c) {
    const int chc = (c + off1) & 31;                   // rotated chunk id
    const int kb = kh * 2048 + chc * 64;               // floats
    unsigned char* buf = wbuf + p * 8192;
    #pragma unroll
    for (int i = 0; i < 4; ++i) {
      const int  r  = i * 4 + g;                       // row_local 0..15
      const unsigned cb = ((unsigned)(l4 * 16)) ^ ((unsigned)(r & 7) << 4);
      const long goff = (rowg + r) * (long)D_DIM + kb + (cb >> 2);
      async_ld16(base + goff, buf + i * 1024);         // dest: uniform + lane*16
      async_ld16(srcp + goff, buf + 4096 + i * 1024);
    }
  };

  auto compute = [&](int p, int c) {
    const int chc = (c + off1) & 31;                   // rotated chunk id
    const int kb = kh * 2048 + chc * 64;
    const unsigned char* buf = wbuf + p * 8192;
    uint4 af[2];
    #pragma unroll
    for (int s = 0; s < 2; ++s) {
      const unsigned x = (unsigned)(l4 & 7) << 4;
      const unsigned cb0 = ((unsigned)(s * 128 + g * 32 +  0)) ^ x;
      const unsigned cb1 = ((unsigned)(s * 128 + g * 32 + 16)) ^ x;
      float4 fb0 = *(const float4*)(buf + l4 * 256 + cb0);
      float4 fb1 = *(const float4*)(buf + l4 * 256 + cb1);
      float4 fs0 = *(const float4*)(buf + 4096 + l4 * 256 + cb0);
      float4 fs1 = *(const float4*)(buf + 4096 + l4 * 256 + cb1);
      af[s].x = pack2bf(fs0.x - fb0.x, fs0.y - fb0.y);
      af[s].y = pack2bf(fs0.z - fb0.z, fs0.w - fb0.w);
      af[s].z = pack2bf(fs1.x - fb1.x, fs1.y - fb1.y);
      af[s].w = pack2bf(fs1.z - fb1.z, fs1.w - fb1.w);
    }
    #pragma unroll
    for (int t = 0; t < 4; ++t) {
      #pragma unroll
      for (int s = 0; s < 2; ++s) {
        uint4 bfrag;
        if (USE_WS) {
          bfrag = *(const uint4*)(Wt_bf + (size_t)(t * 16 + l4) * D_DIM +
                                  kb + s * 32 + g * 8);
        } else {
          unsigned int pq[4];
          #pragma unroll
          for (int e2 = 0; e2 < 4; ++e2) {
            float wa = W[(size_t)(kb + s * 32 + g * 8 + e2 * 2    ) * R_DIM + t * 16 + l4];
            float wb = W[(size_t)(kb + s * 32 + g * 8 + e2 * 2 + 1) * R_DIM + t * 16 + l4];
            pq[e2] = pack2bf(wa, wb);
          }
          bfrag.x = pq[0]; bfrag.y = pq[1]; bfrag.z = pq[2]; bfrag.w = pq[3];
        }
        acc[t] = __builtin_amdgcn_mfma_f32_16x16x32_bf16(
            __builtin_bit_cast(bf16vec8, af[s]),
            __builtin_bit_cast(bf16vec8, bfrag), acc[t], 0, 0, 0);
      }
    }
  };

  stage(0, 0);
  #pragma unroll 1
  for (int c = 0; c < 31; ++c) {
    stage((c + 1) & 1, c + 1);     // prefetch next chunk (async, no VGPRs)
    compute(c & 1, c);
  }
  compute(1, 31);

  // per-wave partials -> own staging buf0 (dead now): [16][72] f32
  {
    float* part = (float*)wbuf;
    #pragma unroll
    for (int t = 0; t < 4; ++t)
      #pragma unroll
      for (int i = 0; i < 4; ++i)
        part[(g * 4 + i) * 72 + t * 16 + l4] = acc[t][i];
  }
  __syncthreads();

  // ---------------- Reduce K-halves + per-row partition mask --------------
  {
    const int row = tid >> 3, jg = tid & 7;     // 64 rows x 8 j-groups
    const int lr  = row & 15;
    const float* pa = (const float*)(smem + ((row >> 4) * 2 + 0) * WAVESTG);
    const float* pb = (const float*)(smem + ((row >> 4) * 2 + 1) * WAVESTG);
    int4 sb = *(const int4*)(subs + (rowbase + row) * 4);
    unsigned mbits = (1u << sb.x) | (1u << sb.y) | (1u << sb.z) | (1u << sb.w);
    unsigned short v[8];
    #pragma unroll
    for (int jj = 0; jj < 8; ++jj) {
      const int j = jg * 8 + jj;
      float sum = pa[lr * 72 + j] + pb[lr * 72 + j];
      v[jj] = ((mbits >> (j >> 3)) & 1u) ? (unsigned short)f2bf_u(sum)
                                         : (unsigned short)0;
    }
    uint4 pk;
    pk.x = (unsigned)v[0] | ((unsigned)v[1] << 16);
    pk.y = (unsigned)v[2] | ((unsigned)v[3] << 16);
    pk.z = (unsigned)v[4] | ((unsigned)v[5] << 16);
    pk.w = (unsigned)v[6] | ((unsigned)v[7] << 16);
    *(uint4*)(smem + OFF_RM + row * 144 + jg * 16) = pk;   // stride 72 shorts
  }
  __syncthreads();

  // ---------------- Phase 2: out = base(global) + rm @ W^T ----------------
  // wave (rq,kh): rows rq*16..+15, cols kh*2048..+2047 in 32 groups of 64.
  uint4 a2[2];
  #pragma unroll
  for (int s = 0; s < 2; ++s)
    a2[s] = *(const uint4*)(smem + OFF_RM + (rq * 16 + l4) * 144 +
                            s * 64 + g * 16);
  float* cbuf = (float*)wbuf;     // [16][72] f32, wave-private
  #pragma unroll 1
  for (int grp = 0; grp < 32; ++grp) {
    const int ga = (grp + off2) & 31;           // rotated column group
    const int cbase = kh * 2048 + ga * 64;
    // base re-read (L2/L3-hot), issued early, independent of MFMAs
    float4 bb[4];
    #pragma unroll
    for (int v2 = 0; v2 < 4; ++v2) {
      const int r = rq * 16 + g + v2 * 4;
      bb[v2] = *(const float4*)(base + (rowbase + r) * D_DIM + cbase + l4 * 4);
    }
    f32x4v a[4];
    #pragma unroll
    for (int t = 0; t < 4; ++t) a[t] = (f32x4v){0.f, 0.f, 0.f, 0.f};
    #pragma unroll
    for (int t = 0; t < 4; ++t) {
      #pragma unroll
      for (int s = 0; s < 2; ++s) {
        uint4 bfrag;  // B[kk=j][n=col] = W[col][j]; per-lane 8 consecutive j
        if (USE_WS) {
          bfrag = *(const uint4*)(Wb_bf + (size_t)(cbase + t * 16 + l4) * R_DIM +
                                  s * 32 + g * 8);
        } else {
          const float* wp = W + (size_t)(cbase + t * 16 + l4) * R_DIM + s * 32 + g * 8;
          float4 wa = *(const float4*)(wp);
          float4 wb2 = *(const float4*)(wp + 4);
          bfrag.x = pack2bf(wa.x, wa.y); bfrag.y = pack2bf(wa.z, wa.w);
          bfrag.z = pack2bf(wb2.x, wb2.y); bfrag.w = pack2bf(wb2.z, wb2.w);
        }
        a[t] = __builtin_amdgcn_mfma_f32_16x16x32_bf16(
            __builtin_bit_cast(bf16vec8, a2[s]),
            __builtin_bit_cast(bf16vec8, bfrag), a[t], 0, 0, 0);
      }
    }
    #pragma unroll
    for (int t = 0; t < 4; ++t)
      #pragma unroll
      for (int i = 0; i < 4; ++i)
        cbuf[(g * 4 + i) * 72 + t * 16 + l4] = a[t][i];
    // transpose via wave-local LDS -> coalesced float4 stores
    #pragma unroll
    for (int v2 = 0; v2 < 4; ++v2) {
      const int r = rq * 16 + g + v2 * 4;
      f32x4v cv = *(const f32x4v*)(cbuf + (g + v2 * 4) * 72 + l4 * 4);
      float4 o;
      o.x = cv[0] + bb[v2].x;
      o.y = cv[1] + bb[v2].y;
      o.z = cv[2] + bb[v2].z;
      o.w = cv[3] + bb[v2].w;
      *(float4*)(out + (rowbase + r) * D_DIM + cbase + l4 * 4) = o;
    }
  }
}

extern "C" void kernel_launch(void* const* d_in, const int* in_sizes, int n_in,
                              void* d_out, int out_size, void* d_ws, size_t ws_size,
                              hipStream_t stream) {
  const float* base = (const float*)d_in[0];
  const float* srcp = (const float*)d_in[1];
  const float* W    = (const float*)d_in[2];
  const int*   subs = (const int*)d_in[3];
  float* out = (float*)d_out;

  const int nblocks = 16384 / BM;   // 256 = 8 XCDs x 32
  const size_t wbytes = (size_t)2 * R_DIM * D_DIM * sizeof(unsigned short); // 1 MB
  if (d_ws && ws_size >= wbytes) {
    unsigned short* Wt = (unsigned short*)d_ws;          // [64][4096] bf16
    unsigned short* Wb = Wt + (size_t)R_DIM * D_DIM;     // [4096][64] bf16
    lrri_prep<<<256, 256, 0, stream>>>(W, Wt, Wb);
    lrri_fused<true><<<nblocks, 512, 0, stream>>>(base, srcp, W, subs, Wt, Wb, out);
  } else {
    lrri_fused<false><<<nblocks, 512, 0, stream>>>(base, srcp, W, subs, nullptr, nullptr, out);
  }
}

// Round 15
// 240.135 us; speedup vs baseline: 1.0416x; 1.0416x over previous
//
#include <hip/hip_runtime.h>

// LowRankRotatedSpaceIntervention — v15: phase-split discriminating experiment.
// out[b,:] = base[b,:] + (mask_b . ((source[b,:]-base[b,:]) @ W)) @ W^T
// B=16384, D=4096, R=64, 8 partitions of 8, 4 selected per row.
//
// 14 rounds: every per-phase theory (occupancy, MLP, ledger, contiguity,
// W placement, XCD map, footprint) is measured-neutral; best results cluster
// at ~230us across different structures AND different traffic volumes.
// v15 splits v11 at the rm boundary (2MB ws buffer): K1 = v11 phase 1
// (read 537MB, write 2MB rm), K2 = v11 phase 2 (read base+rm, write out).
// Each kernel is a single-mode streamer and rocprof now gives PER-PHASE BW.
// Decision rule: both <=3.2 TB/s -> plateau is structural, v11 is roofline;
// either >=4 -> bottleneck localized, attack the slow phase.

#define D_DIM 4096
#define R_DIM 64
#define BM    32
#define WAVESTG 16384            // K1 per-wave: 2 chunk-slots x 8KB
#define K1_SMEM 65536            // 4 wave regions
#define OFF_RM  65536            // fused fallback only
#define FUSED_SMEM 70144

typedef short bf16vec8 __attribute__((ext_vector_type(8)));
typedef float f32x4v  __attribute__((ext_vector_type(4)));

#define VMWAIT(N)                                              \
  do {                                                         \
    asm volatile("s_waitcnt vmcnt(" #N ")" ::: "memory");      \
    __builtin_amdgcn_sched_barrier(0);                         \
  } while (0)

__device__ __forceinline__ unsigned int f2bf_u(float f) {
  unsigned int u = __builtin_bit_cast(unsigned int, f);
  return (u + 0x7fffu + ((u >> 16) & 1u)) >> 16;   // RNE
}
__device__ __forceinline__ unsigned int pack2bf(float a, float b) {
  return f2bf_u(a) | (f2bf_u(b) << 16);
}
__device__ __forceinline__ void async_ld16(const void* g, void* l) {
  __builtin_amdgcn_global_load_lds(
      (const __attribute__((address_space(1))) void*)g,
      (__attribute__((address_space(3))) void*)l, 16, 0, 0);
}

__global__ __launch_bounds__(256)
void lrri_prep(const float* __restrict__ W, unsigned short* __restrict__ Wt,
               unsigned short* __restrict__ Wb) {
  const int idx = blockIdx.x * blockDim.x + threadIdx.x;   // 0..65535
  const int k = idx >> 4;
  const int j = (idx & 15) * 4;
  float4 w = *(const float4*)(W + (size_t)k * R_DIM + j);
  ushort4 p;
  p.x = (unsigned short)f2bf_u(w.x);
  p.y = (unsigned short)f2bf_u(w.y);
  p.z = (unsigned short)f2bf_u(w.z);
  p.w = (unsigned short)f2bf_u(w.w);
  *(ushort4*)(Wb + (size_t)k * R_DIM + j) = p;     // [4096][64] bf16
  Wt[(size_t)(j + 0) * D_DIM + k] = p.x;           // [64][4096] bf16
  Wt[(size_t)(j + 1) * D_DIM + k] = p.y;
  Wt[(size_t)(j + 2) * D_DIM + k] = p.z;
  Wt[(size_t)(j + 3) * D_DIM + k] = p.w;
}

// ===================== K1: rm = mask . ((src-base) @ W)  [v11 phase 1] =====
__global__ __launch_bounds__(256, 2)
void k1_rotdiff(const float* __restrict__ base, const float* __restrict__ srcp,
                const int* __restrict__ subs,
                const unsigned short* __restrict__ Wt_bf,   // [64][4096]
                unsigned short* __restrict__ rm_g)          // [16384][64]
{
  __shared__ __align__(16) unsigned char smem[K1_SMEM];
  const int tid  = threadIdx.x;
  const int wave = tid >> 6;
  const int lane = tid & 63;
  const int l4   = lane & 15;
  const int g    = lane >> 4;
  const int rh   = wave >> 1;            // row-half: 16 rows
  const int kh   = wave & 1;             // K-half: 2048 cols
  const long rowbase = (long)blockIdx.x * BM;
  const long rowg    = rowbase + rh * 16;
  unsigned char* wbuf = smem + wave * WAVESTG;
  const int off1 = (blockIdx.x * 7) & 63;

  f32x4v acc[4];
  #pragma unroll
  for (int t = 0; t < 4; ++t) acc[t] = (f32x4v){0.f, 0.f, 0.f, 0.f};

  auto stage = [&](int c) {                       // 8 gload_lds, order-pinned
    const int ch = (c + off1) & 63;
    unsigned char* buf = wbuf + (c & 1) * 8192;
    const long colf = kh * 2048 + ch * 32;
    #pragma unroll
    for (int q = 0; q < 2; ++q) {
      const int r = q * 8 + (lane >> 3);
      const unsigned b = ((unsigned)((lane & 7) * 16)) ^ ((unsigned)(r & 7) << 4);
      const long goff = (rowg + r) * (long)D_DIM + colf + (b >> 2);
      async_ld16(base + goff, buf + q * 1024);
    }
    #pragma unroll
    for (int q = 0; q < 2; ++q) {
      const int r = q * 8 + (lane >> 3);
      const unsigned b = ((unsigned)((lane & 7) * 16)) ^ ((unsigned)(r & 7) << 4);
      const long goff = (rowg + r) * (long)D_DIM + colf + (b >> 2);
      async_ld16(srcp + goff, buf + 2048 + q * 1024);
    }
    #pragma unroll
    for (int q = 0; q < 4; ++q) {
      const int j = q * 16 + (lane >> 2);
      const unsigned kb = ((unsigned)((lane & 3) * 16)) ^ ((unsigned)(j & 3) << 4);
      const char* src = (const char*)Wt_bf + (size_t)j * (D_DIM * 2) +
                        colf * 2 + kb;
      async_ld16(src, buf + 4096 + q * 1024);
    }
  };

  auto compute = [&](int c) {
    const unsigned char* buf = wbuf + (c & 1) * 8192;
    const unsigned sw = (unsigned)((l4 & 7) << 4);
    const unsigned c0 = ((unsigned)(g * 32)) ^ sw;
    const unsigned c1 = ((unsigned)(g * 32 + 16)) ^ sw;
    float4 fb0 = *(const float4*)(buf + l4 * 128 + c0);
    float4 fb1 = *(const float4*)(buf + l4 * 128 + c1);
    float4 fs0 = *(const float4*)(buf + 2048 + l4 * 128 + c0);
    float4 fs1 = *(const float4*)(buf + 2048 + l4 * 128 + c1);
    uint4 af;
    af.x = pack2bf(fs0.x - fb0.x, fs0.y - fb0.y);
    af.y = pack2bf(fs0.z - fb0.z, fs0.w - fb0.w);
    af.z = pack2bf(fs1.x - fb1.x, fs1.y - fb1.y);
    af.w = pack2bf(fs1.z - fb1.z, fs1.w - fb1.w);
    const unsigned wsl = ((unsigned)(g * 16)) ^ ((unsigned)(l4 & 3) << 4);
    #pragma unroll
    for (int t = 0; t < 4; ++t) {
      uint4 wf = *(const uint4*)(buf + 4096 + (t * 16 + l4) * 64 + wsl);
      acc[t] = __builtin_amdgcn_mfma_f32_16x16x32_bf16(
          __builtin_bit_cast(bf16vec8, af),
          __builtin_bit_cast(bf16vec8, wf), acc[t], 0, 0, 0);
    }
  };

  stage(0); stage(1);
  #pragma unroll 1
  for (int c = 0; c < 62; ++c) {
    VMWAIT(8);
    compute(c);
    __builtin_amdgcn_sched_barrier(0);
    stage(c + 2);
  }
  VMWAIT(8);
  compute(62);
  VMWAIT(0);
  compute(63);

  // per-wave partials -> own staging area: [16][72] f32
  {
    float* part = (float*)wbuf;
    #pragma unroll
    for (int t = 0; t < 4; ++t)
      #pragma unroll
      for (int i = 0; i < 4; ++i)
        part[(g * 4 + i) * 72 + t * 16 + l4] = acc[t][i];
  }
  __syncthreads();

  // reduce K-halves + mask -> GLOBAL rm (coalesced 16B/thread)
  {
    const int row = tid >> 3, jg = tid & 7;     // 32 rows x 8 j-groups
    const int lr  = row & 15;
    const float* pa = (const float*)(smem + ((row >> 4) * 2 + 0) * WAVESTG);
    const float* pb = (const float*)(smem + ((row >> 4) * 2 + 1) * WAVESTG);
    int4 sb = *(const int4*)(subs + (rowbase + row) * 4);
    unsigned mbits = (1u << sb.x) | (1u << sb.y) | (1u << sb.z) | (1u << sb.w);
    unsigned short v[8];
    #pragma unroll
    for (int jj = 0; jj < 8; ++jj) {
      const int j = jg * 8 + jj;
      float sum = pa[lr * 72 + j] + pb[lr * 72 + j];
      v[jj] = ((mbits >> (j >> 3)) & 1u) ? (unsigned short)f2bf_u(sum)
                                         : (unsigned short)0;
    }
    uint4 pk;
    pk.x = (unsigned)v[0] | ((unsigned)v[1] << 16);
    pk.y = (unsigned)v[2] | ((unsigned)v[3] << 16);
    pk.z = (unsigned)v[4] | ((unsigned)v[5] << 16);
    pk.w = (unsigned)v[6] | ((unsigned)v[7] << 16);
    *(uint4*)(rm_g + (rowbase + row) * 64 + jg * 8) = pk;
  }
}

// ===================== K2: out = base + rm @ W^T  [v11 phase 2] ===========
__global__ __launch_bounds__(256, 4)
void k2_apply(const float* __restrict__ base,
              const unsigned short* __restrict__ rm_g,     // [16384][64]
              const unsigned short* __restrict__ Wb_bf,    // [4096][64]
              float* __restrict__ out)
{
  __shared__ __align__(16) unsigned char smem[36864];   // 4 x [32][72] f32
  const int tid  = threadIdx.x;
  const int wave = tid >> 6;
  const int lane = tid & 63;
  const int l4   = lane & 15;
  const int g    = lane >> 4;
  const long rowbase = (long)blockIdx.x * BM;
  const int off2 = (blockIdx.x * 5) & 15;

  uint4 a2[2][2];     // [row-tile m][k-split s] from global rm (L2-hot, 2MB)
  #pragma unroll
  for (int m = 0; m < 2; ++m)
    #pragma unroll
    for (int s = 0; s < 2; ++s)
      a2[m][s] = *(const uint4*)(rm_g + (rowbase + m * 16 + l4) * 64 +
                                 s * 32 + g * 8);

  float* cbuf = (float*)(smem + wave * 9216);   // [32][72] f32, wave-private
  #pragma unroll 1
  for (int grp = 0; grp < 16; ++grp) {
    const int ga = (grp + off2) & 15;
    const int cbase = wave * 1024 + ga * 64;
    float4 bb[8];
    #pragma unroll
    for (int v2 = 0; v2 < 8; ++v2) {
      const int r = g + v2 * 4;
      bb[v2] = *(const float4*)(base + (rowbase + r) * D_DIM + cbase + l4 * 4);
    }
    f32x4v a[2][4];
    #pragma unroll
    for (int m = 0; m < 2; ++m)
      #pragma unroll
      for (int t = 0; t < 4; ++t) a[m][t] = (f32x4v){0.f, 0.f, 0.f, 0.f};
    #pragma unroll
    for (int t = 0; t < 4; ++t) {
      #pragma unroll
      for (int s = 0; s < 2; ++s) {
        uint4 bfrag = *(const uint4*)(Wb_bf +
            (size_t)(cbase + t * 16 + l4) * R_DIM + s * 32 + g * 8);
        #pragma unroll
        for (int m = 0; m < 2; ++m)
          a[m][t] = __builtin_amdgcn_mfma_f32_16x16x32_bf16(
              __builtin_bit_cast(bf16vec8, a2[m][s]),
              __builtin_bit_cast(bf16vec8, bfrag), a[m][t], 0, 0, 0);
      }
    }
    #pragma unroll
    for (int m = 0; m < 2; ++m)
      #pragma unroll
      for (int t = 0; t < 4; ++t)
        #pragma unroll
        for (int i = 0; i < 4; ++i)
          cbuf[(m * 16 + g * 4 + i) * 72 + t * 16 + l4] = a[m][t][i];
    __syncthreads();   // cheap: wave-private cbuf, but keep write->read safe
    #pragma unroll
    for (int v2 = 0; v2 < 8; ++v2) {
      const int r = g + v2 * 4;
      f32x4v cv = *(const f32x4v*)(cbuf + r * 72 + l4 * 4);
      float4 o;
      o.x = cv[0] + bb[v2].x;
      o.y = cv[1] + bb[v2].y;
      o.z = cv[2] + bb[v2].z;
      o.w = cv[3] + bb[v2].w;
      *(float4*)(out + (rowbase + r) * D_DIM + cbase + l4 * 4) = o;
    }
    __syncthreads();
  }
}

// ===================== fused fallback (v11, USE_WS=false) =================
__global__ __launch_bounds__(256, 2)
void lrri_fused_nows(const float* __restrict__ base, const float* __restrict__ srcp,
                     const float* __restrict__ W, const int* __restrict__ subs,
                     float* __restrict__ out)
{
  __shared__ __align__(16) unsigned char smem[FUSED_SMEM];
  const int tid  = threadIdx.x;
  const int wave = tid >> 6;
  const int lane = tid & 63;
  const int l4   = lane & 15;
  const int g    = lane >> 4;
  const int rh   = wave >> 1;
  const int kh   = wave & 1;
  const long rowbase = (long)blockIdx.x * BM;
  const long rowg    = rowbase + rh * 16;
  unsigned char* wbuf = smem + wave * WAVESTG;
  const int off1 = (blockIdx.x * 7) & 63;
  const int off2 = (blockIdx.x * 5) & 15;

  f32x4v acc[4];
  #pragma unroll
  for (int t = 0; t < 4; ++t) acc[t] = (f32x4v){0.f, 0.f, 0.f, 0.f};

  #pragma unroll 1
  for (int c = 0; c < 64; ++c) {
    const int ch = (c + off1) & 63;
    unsigned char* buf = wbuf + (c & 1) * 8192;
    const long colf = kh * 2048 + ch * 32;
    #pragma unroll
    for (int q = 0; q < 2; ++q) {
      const int r = q * 8 + (lane >> 3);
      const unsigned b = ((unsigned)((lane & 7) * 16)) ^ ((unsigned)(r & 7) << 4);
      const long goff = (rowg + r) * (long)D_DIM + colf + (b >> 2);
      async_ld16(base + goff, buf + q * 1024);
      async_ld16(srcp + goff, buf + 2048 + q * 1024);
    }
    VMWAIT(0);
    const unsigned sw = (unsigned)((l4 & 7) << 4);
    const unsigned c0 = ((unsigned)(g * 32)) ^ sw;
    const unsigned c1 = ((unsigned)(g * 32 + 16)) ^ sw;
    float4 fb0 = *(const float4*)(buf + l4 * 128 + c0);
    float4 fb1 = *(const float4*)(buf + l4 * 128 + c1);
    float4 fs0 = *(const float4*)(buf + 2048 + l4 * 128 + c0);
    float4 fs1 = *(const float4*)(buf + 2048 + l4 * 128 + c1);
    uint4 af;
    af.x = pack2bf(fs0.x - fb0.x, fs0.y - fb0.y);
    af.y = pack2bf(fs0.z - fb0.z, fs0.w - fb0.w);
    af.z = pack2bf(fs1.x - fb1.x, fs1.y - fb1.y);
    af.w = pack2bf(fs1.z - fb1.z, fs1.w - fb1.w);
    #pragma unroll
    for (int t = 0; t < 4; ++t) {
      unsigned int pq[4];
      #pragma unroll
      for (int e2 = 0; e2 < 4; ++e2) {
        float wa = W[(size_t)(colf + g * 8 + e2 * 2    ) * R_DIM + t * 16 + l4];
        float wb = W[(size_t)(colf + g * 8 + e2 * 2 + 1) * R_DIM + t * 16 + l4];
        pq[e2] = pack2bf(wa, wb);
      }
      uint4 wf; wf.x = pq[0]; wf.y = pq[1]; wf.z = pq[2]; wf.w = pq[3];
      acc[t] = __builtin_amdgcn_mfma_f32_16x16x32_bf16(
          __builtin_bit_cast(bf16vec8, af),
          __builtin_bit_cast(bf16vec8, wf), acc[t], 0, 0, 0);
    }
  }

  {
    float* part = (float*)wbuf;
    #pragma unroll
    for (int t = 0; t < 4; ++t)
      #pragma unroll
      for (int i = 0; i < 4; ++i)
        part[(g * 4 + i) * 72 + t * 16 + l4] = acc[t][i];
  }
  __syncthreads();

  {
    const int row = tid >> 3, jg = tid & 7;
    const int lr  = row & 15;
    const float* pa = (const float*)(smem + ((row >> 4) * 2 + 0) * WAVESTG);
    const float* pb = (const float*)(smem + ((row >> 4) * 2 + 1) * WAVESTG);
    int4 sb = *(const int4*)(subs + (rowbase + row) * 4);
    unsigned mbits = (1u << sb.x) | (1u << sb.y) | (1u << sb.z) | (1u << sb.w);
    unsigned short v[8];
    #pragma unroll
    for (int jj = 0; jj < 8; ++jj) {
      const int j = jg * 8 + jj;
      float sum = pa[lr * 72 + j] + pb[lr * 72 + j];
      v[jj] = ((mbits >> (j >> 3)) & 1u) ? (unsigned short)f2bf_u(sum)
                                         : (unsigned short)0;
    }
    uint4 pk;
    pk.x = (unsigned)v[0] | ((unsigned)v[1] << 16);
    pk.y = (unsigned)v[2] | ((unsigned)v[3] << 16);
    pk.z = (unsigned)v[4] | ((unsigned)v[5] << 16);
    pk.w = (unsigned)v[6] | ((unsigned)v[7] << 16);
    *(uint4*)(smem + OFF_RM + row * 144 + jg * 16) = pk;
  }
  __syncthreads();

  uint4 a2[2][2];
  #pragma unroll
  for (int m = 0; m < 2; ++m)
    #pragma unroll
    for (int s = 0; s < 2; ++s)
      a2[m][s] = *(const uint4*)(smem + OFF_RM + (m * 16 + l4) * 144 +
                                 s * 64 + g * 16);
  float* cbuf = (float*)wbuf;
  #pragma unroll 1
  for (int grp = 0; grp < 16; ++grp) {
    const int ga = (grp + off2) & 15;
    const int cbase = wave * 1024 + ga * 64;
    float4 bb[8];
    #pragma unroll
    for (int v2 = 0; v2 < 8; ++v2) {
      const int r = g + v2 * 4;
      bb[v2] = *(const float4*)(base + (rowbase + r) * D_DIM + cbase + l4 * 4);
    }
    f32x4v a[2][4];
    #pragma unroll
    for (int m = 0; m < 2; ++m)
      #pragma unroll
      for (int t = 0; t < 4; ++t) a[m][t] = (f32x4v){0.f, 0.f, 0.f, 0.f};
    #pragma unroll
    for (int t = 0; t < 4; ++t) {
      #pragma unroll
      for (int s = 0; s < 2; ++s) {
        const float* wp = W + (size_t)(cbase + t * 16 + l4) * R_DIM + s * 32 + g * 8;
        float4 wa = *(const float4*)(wp);
        float4 wb2 = *(const float4*)(wp + 4);
        uint4 bfrag;
        bfrag.x = pack2bf(wa.x, wa.y); bfrag.y = pack2bf(wa.z, wa.w);
        bfrag.z = pack2bf(wb2.x, wb2.y); bfrag.w = pack2bf(wb2.z, wb2.w);
        #pragma unroll
        for (int m = 0; m < 2; ++m)
          a[m][t] = __builtin_amdgcn_mfma_f32_16x16x32_bf16(
              __builtin_bit_cast(bf16vec8, a2[m][s]),
              __builtin_bit_cast(bf16vec8, bfrag), a[m][t], 0, 0, 0);
      }
    }
    #pragma unroll
    for (int m = 0; m < 2; ++m)
      #pragma unroll
      for (int t = 0; t < 4; ++t)
        #pragma unroll
        for (int i = 0; i < 4; ++i)
          cbuf[(m * 16 + g * 4 + i) * 72 + t * 16 + l4] = a[m][t][i];
    #pragma unroll
    for (int v2 = 0; v2 < 8; ++v2) {
      const int r = g + v2 * 4;
      f32x4v cv = *(const f32x4v*)(cbuf + r * 72 + l4 * 4);
      float4 o;
      o.x = cv[0] + bb[v2].x;
      o.y = cv[1] + bb[v2].y;
      o.z = cv[2] + bb[v2].z;
      o.w = cv[3] + bb[v2].w;
      *(float4*)(out + (rowbase + r) * D_DIM + cbase + l4 * 4) = o;
    }
  }
}

extern "C" void kernel_launch(void* const* d_in, const int* in_sizes, int n_in,
                              void* d_out, int out_size, void* d_ws, size_t ws_size,
                              hipStream_t stream) {
  const float* base = (const float*)d_in[0];
  const float* srcp = (const float*)d_in[1];
  const float* W    = (const float*)d_in[2];
  const int*   subs = (const int*)d_in[3];
  float* out = (float*)d_out;

  const int nblocks = 16384 / BM;   // 512
  const size_t wconv = (size_t)2 * R_DIM * D_DIM * sizeof(unsigned short); // 1 MB
  const size_t rmsz  = (size_t)16384 * R_DIM * sizeof(unsigned short);     // 2 MB
  if (d_ws && ws_size >= wconv + rmsz) {
    unsigned short* Wt = (unsigned short*)d_ws;          // [64][4096] bf16
    unsigned short* Wb = Wt + (size_t)R_DIM * D_DIM;     // [4096][64] bf16
    unsigned short* rm = Wb + (size_t)R_DIM * D_DIM;     // [16384][64] bf16
    lrri_prep<<<256, 256, 0, stream>>>(W, Wt, Wb);
    k1_rotdiff<<<nblocks, 256, 0, stream>>>(base, srcp, subs, Wt, rm);
    k2_apply<<<nblocks, 256, 0, stream>>>(base, rm, Wb, out);
  } else {
    lrri_fused_nows<<<nblocks, 256, 0, stream>>>(base, srcp, W, subs, out);
  }
}